// Round 3
// baseline (1310.148 us; speedup 1.0000x reference)
//
#include <hip/hip_runtime.h>
#include <hip/hip_cooperative_groups.h>

namespace cg = cooperative_groups;

#define N_ENT 4096
#define N_REL 4
#define FDIM 128
#define KDIM 512      // N_REL * FDIM
#define MAXNZ 128     // binomial(4096,0.01): mean 41, std 6.4; 128 is >13 sigma
#define BATCH 8192
#define NROWS (N_REL * N_ENT)
#define GRID 1024     // 4 blocks/CU * 256 CUs -> exact cooperative co-residency

typedef float f4v __attribute__((ext_vector_type(4)));

// Union of per-phase LDS needs; phases are separated by grid.sync().
union SharedU {
  struct {
    unsigned short sc[MAXNZ];
    float part[8][FDIM];
    int lcnt;
  } a;
  struct {
    unsigned short lc[4][N_REL][MAXNZ];   // 4 KB
    float aggL[4][KDIM];                  // 8 KB
    float red[4][FDIM];                   // 2 KB
  } c;
  struct {
    float red[4][FDIM];
  } b;
};

// ---------------------------------------------------------------------------
// Fused cooperative kernel. Phase boundaries now carry a FULL release/acquire
// pair: __threadfence_system() BEFORE grid.sync() (writer release: L2
// writeback past the XCD boundary) and AFTER grid.sync() (reader acquire:
// invalidate local L1/L2 so we don't hit stale poison lines left by the
// harness workspace fill). R2's race was the missing acquire side.
// ---------------------------------------------------------------------------
__global__ __launch_bounds__(256, 4) void k_fused(
    const float* __restrict__ W1, const float* __restrict__ W2,
    const float* __restrict__ M, const float* __restrict__ adj,
    const float* __restrict__ feat,
    const int* __restrict__ e1, const int* __restrict__ rel,
    const int* __restrict__ e2,
    float* __restrict__ W1T, float* __restrict__ W2T,
    float* __restrict__ diagM,
    unsigned short* __restrict__ cols, int* __restrict__ cnt,
    float* __restrict__ inv_deg, float* __restrict__ agg,
    float* __restrict__ h1, float* __restrict__ h2,
    float* __restrict__ out) {
  cg::grid_group grid = cg::this_grid();
  __shared__ __align__(16) union SharedU S;
  const int tid = threadIdx.x;

  // ===================== Phase A: prep =====================
  for (int u = blockIdx.x; u < NROWS + 514; u += GRID) {
    if (u < NROWS) {
      int row = u;                 // r*N_ENT + n
      int r = row >> 12;
      int node = row & (N_ENT - 1);
      if (tid == 0) S.a.lcnt = 0;
      __syncthreads();
      const f4v* src = (const f4v*)(adj + (size_t)row * N_ENT);
      int base = tid * 16;
      unsigned mask = 0;
#pragma unroll
      for (int q = 0; q < 4; ++q) {
        f4v v = __builtin_nontemporal_load(src + tid * 4 + q);
        if (v.x != 0.f) mask |= 1u << (q * 4 + 0);
        if (v.y != 0.f) mask |= 1u << (q * 4 + 1);
        if (v.z != 0.f) mask |= 1u << (q * 4 + 2);
        if (v.w != 0.f) mask |= 1u << (q * 4 + 3);
      }
      int mycnt = __popc(mask);
      int p = 0;
      if (mycnt) p = atomicAdd(&S.a.lcnt, mycnt);
      while (mask) {
        int b = __ffs(mask) - 1;
        mask &= mask - 1;
        if (p < MAXNZ) S.a.sc[p] = (unsigned short)(base + b);
        ++p;
      }
      __syncthreads();
      int c = S.a.lcnt; if (c > MAXNZ) c = MAXNZ;
      float w = 1.0f / (float)(c > 0 ? c : 1);
      if (tid < c) cols[(size_t)row * MAXNZ + tid] = S.a.sc[tid];
      if (tid == 0) { cnt[row] = c; inv_deg[row] = w; }
      // fused layer-1 gather: float4 lane l, neighbor group g (8-deep)
      int l = tid & 31;
      int g = tid >> 5;            // 0..7
      const float* fp = feat + l * 4;
      float ax = 0.f, ay = 0.f, az = 0.f, aw = 0.f;
      int j = g;
      for (; j + 8 < c; j += 16) {
        float4 v0 = *(const float4*)(fp + (int)S.a.sc[j] * FDIM);
        float4 v1 = *(const float4*)(fp + (int)S.a.sc[j + 8] * FDIM);
        ax += v0.x + v1.x; ay += v0.y + v1.y;
        az += v0.z + v1.z; aw += v0.w + v1.w;
      }
      if (j < c) {
        float4 v = *(const float4*)(fp + (int)S.a.sc[j] * FDIM);
        ax += v.x; ay += v.y; az += v.z; aw += v.w;
      }
      S.a.part[g][l * 4 + 0] = ax; S.a.part[g][l * 4 + 1] = ay;
      S.a.part[g][l * 4 + 2] = az; S.a.part[g][l * 4 + 3] = aw;
      __syncthreads();
      if (tid < FDIM) {
        float s = 0.f;
#pragma unroll
        for (int gg = 0; gg < 8; ++gg) s += S.a.part[gg][tid];
        agg[(size_t)node * KDIM + r * FDIM + tid] = s * w;
      }
    } else if (u < NROWS + 512) {
      int ab = u - NROWS;
      int id = ab * 256 + tid;     // 0 .. 131071
      int which = id >> 16;
      int e = id & 65535;
      int rr = e >> 14, rem = e & 16383, ff = rem >> 7, o = rem & 127;
      const float* srcw = which ? W2 : W1;
      float* dst = which ? W2T : W1T;
      dst[e] = srcw[(rr * FDIM + o) * FDIM + ff];
    } else {
      int idx = (u - NROWS - 512) * 256 + tid;   // 0 .. 511
      if (idx < 512) {
        int rr = idx >> 7, ff = idx & 127;
        diagM[idx] = M[((size_t)(rr * FDIM + ff)) * FDIM + ff];
      }
    }
  }
  __threadfence_system();   // release: writeback our L2 writes
  grid.sync();
  __threadfence_system();   // acquire: invalidate stale local cache lines

  // ===================== Phase B: h1 = sigmoid(agg @ W1T) =====================
  for (int u = blockIdx.x; u < N_ENT / 4; u += GRID) {
    constexpr int KH = KDIM / 2, Ncol = FDIM;
    int o = tid & 127;
    int half = tid >> 7;
    int n0 = u * 4;
    const float* Ap = agg + (size_t)n0 * KDIM + half * KH;
    const float* Bp = W1T + (size_t)half * KH * Ncol + o;
    float acc[4] = {0.f, 0.f, 0.f, 0.f};
#pragma unroll 2
    for (int k = 0; k < KH; k += 4) {
      float4 a0 = *(const float4*)(Ap + 0 * KDIM + k);
      float4 a1 = *(const float4*)(Ap + 1 * KDIM + k);
      float4 a2 = *(const float4*)(Ap + 2 * KDIM + k);
      float4 a3 = *(const float4*)(Ap + 3 * KDIM + k);
      float b0 = Bp[(size_t)(k + 0) * Ncol];
      float b1 = Bp[(size_t)(k + 1) * Ncol];
      float b2 = Bp[(size_t)(k + 2) * Ncol];
      float b3 = Bp[(size_t)(k + 3) * Ncol];
      acc[0] += a0.x * b0 + a0.y * b1 + a0.z * b2 + a0.w * b3;
      acc[1] += a1.x * b0 + a1.y * b1 + a1.z * b2 + a1.w * b3;
      acc[2] += a2.x * b0 + a2.y * b1 + a2.z * b2 + a2.w * b3;
      acc[3] += a3.x * b0 + a3.y * b1 + a3.z * b2 + a3.w * b3;
    }
    if (half) {
#pragma unroll
      for (int i = 0; i < 4; ++i) S.b.red[i][o] = acc[i];
    }
    __syncthreads();
    if (!half) {
#pragma unroll
      for (int i = 0; i < 4; ++i) {
        float v = acc[i] + S.b.red[i][o];
        v = 1.f / (1.f + __expf(-v));
        h1[(size_t)(n0 + i) * Ncol + o] = v;
      }
    }
    __syncthreads();
  }
  __threadfence_system();
  grid.sync();
  __threadfence_system();

  // ===================== Phase C: layer 2 (gather + GEMM, agg in LDS) ========
  for (int u = blockIdx.x; u < N_ENT / 4; u += GRID) {
    int n0 = u * 4;
    {
      int i = tid >> 4;            // row slot 0..15
      int t16 = tid & 15;
      int nb = i >> 2, r = i & 3;
      int row = r * N_ENT + n0 + nb;
      int c = cnt[row];
      for (int j = t16; j < c; j += 16)
        S.c.lc[nb][r][j] = cols[(size_t)row * MAXNZ + j];
    }
    __syncthreads();
    {
      int l = tid & 31;            // float4 lane
      int g = tid >> 5;            // pair group 0..7
      const float* fp = h1 + l * 4;
#pragma unroll
      for (int q = 0; q < 2; ++q) {
        int pair = g + q * 8;      // 0..15 = nb*4 + r
        int nb = pair >> 2, r = pair & 3;
        int row = r * N_ENT + n0 + nb;
        int c = cnt[row];
        float w = inv_deg[row];
        float ax = 0.f, ay = 0.f, az = 0.f, aw = 0.f;
        int j = 0;
        for (; j + 2 <= c; j += 2) {
          float4 v0 = *(const float4*)(fp + (int)S.c.lc[nb][r][j] * FDIM);
          float4 v1 = *(const float4*)(fp + (int)S.c.lc[nb][r][j + 1] * FDIM);
          ax += v0.x + v1.x; ay += v0.y + v1.y;
          az += v0.z + v1.z; aw += v0.w + v1.w;
        }
        if (j < c) {
          float4 v = *(const float4*)(fp + (int)S.c.lc[nb][r][j] * FDIM);
          ax += v.x; ay += v.y; az += v.z; aw += v.w;
        }
        float4 res; res.x = ax * w; res.y = ay * w; res.z = az * w; res.w = aw * w;
        *(float4*)&S.c.aggL[nb][r * FDIM + l * 4] = res;
      }
    }
    __syncthreads();
    {
      constexpr int KH = KDIM / 2, Ncol = FDIM;
      int o = tid & 127;
      int half = tid >> 7;
      const float* Bp = W2T + (size_t)half * KH * Ncol + o;
      int kbase = half * KH;
      float acc[4] = {0.f, 0.f, 0.f, 0.f};
#pragma unroll 2
      for (int k = 0; k < KH; k += 4) {
        float4 a0 = *(const float4*)&S.c.aggL[0][kbase + k];
        float4 a1 = *(const float4*)&S.c.aggL[1][kbase + k];
        float4 a2 = *(const float4*)&S.c.aggL[2][kbase + k];
        float4 a3 = *(const float4*)&S.c.aggL[3][kbase + k];
        float b0 = Bp[(size_t)(k + 0) * Ncol];
        float b1 = Bp[(size_t)(k + 1) * Ncol];
        float b2 = Bp[(size_t)(k + 2) * Ncol];
        float b3 = Bp[(size_t)(k + 3) * Ncol];
        acc[0] += a0.x * b0 + a0.y * b1 + a0.z * b2 + a0.w * b3;
        acc[1] += a1.x * b0 + a1.y * b1 + a1.z * b2 + a1.w * b3;
        acc[2] += a2.x * b0 + a2.y * b1 + a2.z * b2 + a2.w * b3;
        acc[3] += a3.x * b0 + a3.y * b1 + a3.z * b2 + a3.w * b3;
      }
      if (half) {
#pragma unroll
        for (int i = 0; i < 4; ++i) S.c.red[i][o] = acc[i];
      }
      __syncthreads();
      if (!half) {
#pragma unroll
        for (int i = 0; i < 4; ++i) {
          float v = acc[i] + S.c.red[i][o];
          v = 1.f / (1.f + __expf(-v));
          h2[(size_t)(n0 + i) * Ncol + o] = v;
        }
      }
    }
    __syncthreads();
  }
  __threadfence_system();
  grid.sync();
  __threadfence_system();

  // ===================== Phase D: DistMult scores ============================
  for (int u = blockIdx.x; u < BATCH / 4; u += GRID) {
    int wave = tid >> 6;
    int lane = tid & 63;
    int b = u * 4 + wave;
    int a_ = e1[b], r_ = rel[b], c_ = e2[b];
    const float* hp = h2 + (size_t)a_ * FDIM;
    const float* dp = diagM + (size_t)r_ * FDIM;
    const float* gp = h2 + (size_t)c_ * FDIM;
    float v = hp[lane] * dp[lane] * gp[lane]
            + hp[lane + 64] * dp[lane + 64] * gp[lane + 64];
#pragma unroll
    for (int off = 32; off > 0; off >>= 1) v += __shfl_down(v, off, 64);
    if (lane == 0) out[b] = v;
  }
}

// ===========================================================================
// Fallback path: the verified 4-kernel pipeline from R1 (463 us, passed).
// Used only if the cooperative launch is rejected (e.g. under graph capture).
// ===========================================================================
__global__ __launch_bounds__(256) void k_prep(
    const float* __restrict__ W1, const float* __restrict__ W2,
    const float* __restrict__ M, const float* __restrict__ adj,
    const float* __restrict__ feat,
    float* __restrict__ W1T, float* __restrict__ W2T, float* __restrict__ diagM,
    unsigned short* __restrict__ cols, int* __restrict__ cnt,
    float* __restrict__ inv_deg, float* __restrict__ agg) {
  int blk = blockIdx.x;
  if (blk < NROWS) {
    int row = blk;
    int r = row >> 12;
    int node = row & (N_ENT - 1);
    __shared__ unsigned short sc[MAXNZ];
    __shared__ float part[8][FDIM];
    __shared__ int lcnt;
    if (threadIdx.x == 0) lcnt = 0;
    __syncthreads();
    const f4v* src = (const f4v*)(adj + (size_t)row * N_ENT);
    int base = threadIdx.x * 16;
    unsigned mask = 0;
#pragma unroll
    for (int q = 0; q < 4; ++q) {
      f4v v = __builtin_nontemporal_load(src + threadIdx.x * 4 + q);
      if (v.x != 0.f) mask |= 1u << (q * 4 + 0);
      if (v.y != 0.f) mask |= 1u << (q * 4 + 1);
      if (v.z != 0.f) mask |= 1u << (q * 4 + 2);
      if (v.w != 0.f) mask |= 1u << (q * 4 + 3);
    }
    int mycnt = __popc(mask);
    int p = 0;
    if (mycnt) p = atomicAdd(&lcnt, mycnt);
    while (mask) {
      int b = __ffs(mask) - 1;
      mask &= mask - 1;
      if (p < MAXNZ) sc[p] = (unsigned short)(base + b);
      ++p;
    }
    __syncthreads();
    int c = lcnt; if (c > MAXNZ) c = MAXNZ;
    float w = 1.0f / (float)(c > 0 ? c : 1);
    if (threadIdx.x < c) cols[(size_t)row * MAXNZ + threadIdx.x] = sc[threadIdx.x];
    if (threadIdx.x == 0) { cnt[row] = c; inv_deg[row] = w; }
    int l = threadIdx.x & 31;
    int g = threadIdx.x >> 5;
    const float* fp = feat + l * 4;
    float ax = 0.f, ay = 0.f, az = 0.f, aw = 0.f;
    int j = g;
    for (; j + 8 < c; j += 16) {
      float4 v0 = *(const float4*)(fp + (int)sc[j] * FDIM);
      float4 v1 = *(const float4*)(fp + (int)sc[j + 8] * FDIM);
      ax += v0.x + v1.x; ay += v0.y + v1.y;
      az += v0.z + v1.z; aw += v0.w + v1.w;
    }
    if (j < c) {
      float4 v = *(const float4*)(fp + (int)sc[j] * FDIM);
      ax += v.x; ay += v.y; az += v.z; aw += v.w;
    }
    part[g][l * 4 + 0] = ax; part[g][l * 4 + 1] = ay;
    part[g][l * 4 + 2] = az; part[g][l * 4 + 3] = aw;
    __syncthreads();
    if (threadIdx.x < FDIM) {
      float s = 0.f;
#pragma unroll
      for (int gg = 0; gg < 8; ++gg) s += part[gg][threadIdx.x];
      agg[(size_t)node * KDIM + r * FDIM + threadIdx.x] = s * w;
    }
    return;
  }
  int ab = blk - NROWS;
  if (ab < 512) {
    int id = ab * 256 + threadIdx.x;
    int which = id >> 16;
    int e = id & 65535;
    int rr = e >> 14, rem = e & 16383, ff = rem >> 7, o = rem & 127;
    const float* srcw = which ? W2 : W1;
    float* dst = which ? W2T : W1T;
    dst[e] = srcw[(rr * FDIM + o) * FDIM + ff];
    return;
  }
  int idx = (ab - 512) * 256 + threadIdx.x;
  int rr = idx >> 7, ff = idx & 127;
  diagM[idx] = M[((size_t)(rr * FDIM + ff)) * FDIM + ff];
}

__device__ __forceinline__ void gemm_body(
    const float* __restrict__ A, const float* __restrict__ B,
    float* __restrict__ C, int n0, float (*red)[128]) {
  constexpr int KD = KDIM, KH = KDIM / 2, Ncol = FDIM;
  int o = threadIdx.x & 127;
  int half = threadIdx.x >> 7;
  const float* Ap = A + (size_t)n0 * KD + half * KH;
  const float* Bp = B + (size_t)half * KH * Ncol + o;
  float acc[8] = {0.f, 0.f, 0.f, 0.f, 0.f, 0.f, 0.f, 0.f};
#pragma unroll 2
  for (int k = 0; k < KH; k += 4) {
    float4 a0 = *(const float4*)(Ap + 0 * KD + k);
    float4 a1 = *(const float4*)(Ap + 1 * KD + k);
    float4 a2 = *(const float4*)(Ap + 2 * KD + k);
    float4 a3 = *(const float4*)(Ap + 3 * KD + k);
    float4 a4 = *(const float4*)(Ap + 4 * KD + k);
    float4 a5 = *(const float4*)(Ap + 5 * KD + k);
    float4 a6 = *(const float4*)(Ap + 6 * KD + k);
    float4 a7 = *(const float4*)(Ap + 7 * KD + k);
    float b0 = Bp[(size_t)(k + 0) * Ncol];
    float b1 = Bp[(size_t)(k + 1) * Ncol];
    float b2 = Bp[(size_t)(k + 2) * Ncol];
    float b3 = Bp[(size_t)(k + 3) * Ncol];
    acc[0] += a0.x * b0 + a0.y * b1 + a0.z * b2 + a0.w * b3;
    acc[1] += a1.x * b0 + a1.y * b1 + a1.z * b2 + a1.w * b3;
    acc[2] += a2.x * b0 + a2.y * b1 + a2.z * b2 + a2.w * b3;
    acc[3] += a3.x * b0 + a3.y * b1 + a3.z * b2 + a3.w * b3;
    acc[4] += a4.x * b0 + a4.y * b1 + a4.z * b2 + a4.w * b3;
    acc[5] += a5.x * b0 + a5.y * b1 + a5.z * b2 + a5.w * b3;
    acc[6] += a6.x * b0 + a6.y * b1 + a6.z * b2 + a6.w * b3;
    acc[7] += a7.x * b0 + a7.y * b1 + a7.z * b2 + a7.w * b3;
  }
  if (half) {
#pragma unroll
    for (int i = 0; i < 8; ++i) red[i][o] = acc[i];
  }
  __syncthreads();
  if (!half) {
#pragma unroll
    for (int i = 0; i < 8; ++i) {
      float v = acc[i] + red[i][o];
      v = 1.f / (1.f + __expf(-v));
      C[(size_t)(n0 + i) * Ncol + o] = v;
    }
  }
}

__global__ __launch_bounds__(256) void k_gemm(
    const float* __restrict__ A, const float* __restrict__ B,
    float* __restrict__ C) {
  __shared__ float red[8][128];
  gemm_body(A, B, C, blockIdx.x * 8, red);
}

__global__ __launch_bounds__(256) void k_layer2(
    const unsigned short* __restrict__ cols, const int* __restrict__ cnt,
    const float* __restrict__ inv_deg, const float* __restrict__ h1,
    const float* __restrict__ W2T, float* __restrict__ h2) {
  int n0 = blockIdx.x * 4;
  __shared__ unsigned short lc[4][N_REL][MAXNZ];
  __shared__ __align__(16) float aggL[4][KDIM];
  __shared__ float red[4][128];
  {
    int i = threadIdx.x >> 4;
    int t16 = threadIdx.x & 15;
    int nb = i >> 2, r = i & 3;
    int row = r * N_ENT + n0 + nb;
    int c = cnt[row];
    for (int j = t16; j < c; j += 16)
      lc[nb][r][j] = cols[(size_t)row * MAXNZ + j];
  }
  __syncthreads();
  {
    int l = threadIdx.x & 31;
    int g = threadIdx.x >> 5;
    const float* fp = h1 + l * 4;
#pragma unroll
    for (int q = 0; q < 2; ++q) {
      int pair = g + q * 8;
      int nb = pair >> 2, r = pair & 3;
      int row = r * N_ENT + n0 + nb;
      int c = cnt[row];
      float w = inv_deg[row];
      float ax = 0.f, ay = 0.f, az = 0.f, aw = 0.f;
      int j = 0;
      for (; j + 2 <= c; j += 2) {
        float4 v0 = *(const float4*)(fp + (int)lc[nb][r][j] * FDIM);
        float4 v1 = *(const float4*)(fp + (int)lc[nb][r][j + 1] * FDIM);
        ax += v0.x + v1.x; ay += v0.y + v1.y;
        az += v0.z + v1.z; aw += v0.w + v1.w;
      }
      if (j < c) {
        float4 v = *(const float4*)(fp + (int)lc[nb][r][j] * FDIM);
        ax += v.x; ay += v.y; az += v.z; aw += v.w;
      }
      float4 res; res.x = ax * w; res.y = ay * w; res.z = az * w; res.w = aw * w;
      *(float4*)&aggL[nb][r * FDIM + l * 4] = res;
    }
  }
  __syncthreads();
  {
    constexpr int KH = KDIM / 2, Ncol = FDIM;
    int o = threadIdx.x & 127;
    int half = threadIdx.x >> 7;
    const float* Bp = W2T + (size_t)half * KH * Ncol + o;
    int kbase = half * KH;
    float acc[4] = {0.f, 0.f, 0.f, 0.f};
#pragma unroll 2
    for (int k = 0; k < KH; k += 4) {
      float4 a0 = *(const float4*)&aggL[0][kbase + k];
      float4 a1 = *(const float4*)&aggL[1][kbase + k];
      float4 a2 = *(const float4*)&aggL[2][kbase + k];
      float4 a3 = *(const float4*)&aggL[3][kbase + k];
      float b0 = Bp[(size_t)(k + 0) * Ncol];
      float b1 = Bp[(size_t)(k + 1) * Ncol];
      float b2 = Bp[(size_t)(k + 2) * Ncol];
      float b3 = Bp[(size_t)(k + 3) * Ncol];
      acc[0] += a0.x * b0 + a0.y * b1 + a0.z * b2 + a0.w * b3;
      acc[1] += a1.x * b0 + a1.y * b1 + a1.z * b2 + a1.w * b3;
      acc[2] += a2.x * b0 + a2.y * b1 + a2.z * b2 + a2.w * b3;
      acc[3] += a3.x * b0 + a3.y * b1 + a3.z * b2 + a3.w * b3;
    }
    if (half) {
#pragma unroll
      for (int i = 0; i < 4; ++i) red[i][o] = acc[i];
    }
    __syncthreads();
    if (!half) {
#pragma unroll
      for (int i = 0; i < 4; ++i) {
        float v = acc[i] + red[i][o];
        v = 1.f / (1.f + __expf(-v));
        h2[(size_t)(n0 + i) * Ncol + o] = v;
      }
    }
  }
}

__global__ __launch_bounds__(256) void k_score(
    const float* __restrict__ h, const float* __restrict__ diagM,
    const int* __restrict__ e1, const int* __restrict__ rel,
    const int* __restrict__ e2, float* __restrict__ out) {
  int wave = threadIdx.x >> 6;
  int lane = threadIdx.x & 63;
  int b = blockIdx.x * 4 + wave;
  int a = e1[b], r = rel[b], c = e2[b];
  const float* hp = h + (size_t)a * FDIM;
  const float* dp = diagM + (size_t)r * FDIM;
  const float* gp = h + (size_t)c * FDIM;
  float v = hp[lane] * dp[lane] * gp[lane]
          + hp[lane + 64] * dp[lane + 64] * gp[lane + 64];
#pragma unroll
  for (int off = 32; off > 0; off >>= 1) v += __shfl_down(v, off, 64);
  if (lane == 0) out[b] = v;
}

// ---------------------------------------------------------------------------
extern "C" void kernel_launch(void* const* d_in, const int* in_sizes, int n_in,
                              void* d_out, int out_size, void* d_ws, size_t ws_size,
                              hipStream_t stream) {
  const float* feat = (const float*)d_in[0];
  const float* adj  = (const float*)d_in[1];
  const float* W1   = (const float*)d_in[2];
  const float* W2   = (const float*)d_in[3];
  const float* M    = (const float*)d_in[4];
  const int* e1     = (const int*)d_in[5];
  const int* rel    = (const int*)d_in[6];
  const int* e2     = (const int*)d_in[7];
  float* out = (float*)d_out;

  char* ws = (char*)d_ws;
  unsigned short* cols = (unsigned short*)(ws);                 // 4 MB
  int*   cnt  = (int*)  (ws + 4194304);                         // 64 KB
  float* inv  = (float*)(ws + 4259840);                         // 64 KB
  float* W1T  = (float*)(ws + 4325376);                         // 256 KB
  float* W2T  = (float*)(ws + 4587520);                         // 256 KB
  float* dM   = (float*)(ws + 4849664);                         // 2 KB
  float* agg  = (float*)(ws + 5111808);                         // 8 MB
  float* h1   = (float*)(ws + 13500416);                        // 2 MB
  float* h2   = (float*)(ws + 15597568);                        // 2 MB

  void* args[] = {
    (void*)&W1, (void*)&W2, (void*)&M, (void*)&adj, (void*)&feat,
    (void*)&e1, (void*)&rel, (void*)&e2,
    (void*)&W1T, (void*)&W2T, (void*)&dM,
    (void*)&cols, (void*)&cnt, (void*)&inv, (void*)&agg,
    (void*)&h1, (void*)&h2, (void*)&out
  };
  hipError_t err = hipLaunchCooperativeKernel(
      (const void*)k_fused, dim3(GRID), dim3(256), args, 0, stream);
  if (err != hipSuccess) {
    (void)hipGetLastError();   // clear sticky error, use verified 4-kernel path
    k_prep<<<NROWS + 514, 256, 0, stream>>>(
        W1, W2, M, adj, feat, W1T, W2T, dM, cols, cnt, inv, agg);
    k_gemm<<<N_ENT / 8, 256, 0, stream>>>(agg, W1T, h1);
    k_layer2<<<N_ENT / 4, 256, 0, stream>>>(cols, cnt, inv, h1, W2T, h2);
    k_score<<<BATCH / 4, 256, 0, stream>>>(h2, dM, e1, rel, e2, out);
  }
}

// Round 4
// 432.394 us; speedup vs baseline: 3.0300x; 3.0300x over previous
//
#include <hip/hip_runtime.h>
#include <hip/hip_bf16.h>

#define N_ENT 4096
#define N_REL 4
#define FDIM 128
#define KDIM 512      // N_REL * FDIM
#define MAXNZ 128     // binomial(4096,0.01): mean 41, std 6.4; 128 is >13 sigma
#define BATCH 8192
#define NROWS (N_REL * N_ENT)

typedef float f4v __attribute__((ext_vector_type(4)));

// ---------------------------------------------------------------------------
// K_prep: one launch, two block ranges.
//   blocks [0, NROWS): sparsify one adj row (r,n) + fused layer-1 gather.
//     R4 rework of the sparsify (R3 counters showed latency-bound, not BW):
//       - NO LDS atomics: per-lane popc -> 6-step __shfl_up wave scan ->
//         4 wave totals via LDS -> deterministic scatter offsets.
//         (The old 256-way same-address atomicAdd serializes in the DS unit.)
//       - Coalesced adj loads: each load q is lane-consecutive, so a wave
//         reads one contiguous 1 KB segment per instruction (was stride-64B,
//         4x the cache-line transactions). mask bit (q*4+e) now maps to
//         column w*1024 + q*256 + l*4 + e; compaction order changes, sums
//         are commutative.
//   blocks [NROWS, NROWS+514): W1/W2 transpose + relmat diag extract.
// ---------------------------------------------------------------------------
__global__ __launch_bounds__(256) void k_prep(
    const float* __restrict__ W1, const float* __restrict__ W2,
    const float* __restrict__ M, const float* __restrict__ adj,
    const float* __restrict__ feat,
    float* __restrict__ W1T, float* __restrict__ W2T, float* __restrict__ diagM,
    unsigned short* __restrict__ cols, int* __restrict__ cnt,
    float* __restrict__ inv_deg, float* __restrict__ agg) {
  int blk = blockIdx.x;
  if (blk < NROWS) {
    int row = blk;               // r*N_ENT + n
    int r = row >> 12;
    int node = row & (N_ENT - 1);
    __shared__ unsigned short sc[MAXNZ];
    __shared__ float part[8][FDIM];
    __shared__ int wtot[4];
    int w = threadIdx.x >> 6;    // wave 0..3, owns elements [w*1024, w*1024+1024)
    int l = threadIdx.x & 63;    // lane
    // --- sparsify: 4 coalesced wave-contiguous float4 loads per lane ---
    const f4v* rowp = (const f4v*)(adj + (size_t)row * N_ENT);
    unsigned mask = 0;
#pragma unroll
    for (int q = 0; q < 4; ++q) {
      // float4 index w*256 + q*64 + l: lanes consecutive -> 1 KB/wave/load
      f4v v = __builtin_nontemporal_load(rowp + w * 256 + q * 64 + l);
      if (v.x != 0.f) mask |= 1u << (q * 4 + 0);
      if (v.y != 0.f) mask |= 1u << (q * 4 + 1);
      if (v.z != 0.f) mask |= 1u << (q * 4 + 2);
      if (v.w != 0.f) mask |= 1u << (q * 4 + 3);
    }
    int my = __popc(mask);
    // wave-inclusive prefix scan of per-lane counts (6 shfl_up steps)
    int scan = my;
#pragma unroll
    for (int off = 1; off < 64; off <<= 1) {
      int nb = __shfl_up(scan, off, 64);
      if (l >= off) scan += nb;
    }
    if (l == 63) wtot[w] = scan;       // wave total
    int excl = scan - my;              // lane-exclusive prefix within wave
    __syncthreads();
    int wbase = 0, c = 0;
#pragma unroll
    for (int ww = 0; ww < 4; ++ww) {
      int t = wtot[ww];
      if (ww < w) wbase += t;
      c += t;
    }
    if (c > MAXNZ) c = MAXNZ;
    int p = wbase + excl;
    unsigned m = mask;
    while (m) {
      int b = __ffs(m) - 1;
      m &= m - 1;
      int col = w * 1024 + (b >> 2) * 256 + l * 4 + (b & 3);
      if (p < MAXNZ) sc[p] = (unsigned short)col;
      ++p;
    }
    __syncthreads();
    float wgt = 1.0f / (float)(c > 0 ? c : 1);
    // persist CSR row for layer 2
    if (threadIdx.x < c) cols[(size_t)row * MAXNZ + threadIdx.x] = sc[threadIdx.x];
    if (threadIdx.x == 0) { cnt[row] = c; inv_deg[row] = wgt; }
    // --- fused layer-1 gather: float4 lane ll, neighbor group g (8-deep) ---
    int ll = threadIdx.x & 31;
    int g = threadIdx.x >> 5;          // 0..7
    const float* fp = feat + ll * 4;
    float ax = 0.f, ay = 0.f, az = 0.f, aw = 0.f;
    int j = g;
    for (; j + 8 < c; j += 16) {       // unroll x2: j and j+8 in flight
      float4 v0 = *(const float4*)(fp + (int)sc[j] * FDIM);
      float4 v1 = *(const float4*)(fp + (int)sc[j + 8] * FDIM);
      ax += v0.x + v1.x; ay += v0.y + v1.y;
      az += v0.z + v1.z; aw += v0.w + v1.w;
    }
    if (j < c) {
      float4 v = *(const float4*)(fp + (int)sc[j] * FDIM);
      ax += v.x; ay += v.y; az += v.z; aw += v.w;
    }
    part[g][ll * 4 + 0] = ax; part[g][ll * 4 + 1] = ay;
    part[g][ll * 4 + 2] = az; part[g][ll * 4 + 3] = aw;
    __syncthreads();
    if (threadIdx.x < FDIM) {
      // 128 threads, one output float each; coalesced 512B store segment
      float s = 0.f;
#pragma unroll
      for (int gg = 0; gg < 8; ++gg) s += part[gg][threadIdx.x];
      agg[(size_t)node * KDIM + r * FDIM + threadIdx.x] = s * wgt;
    }
    return;
  }
  int ab = blk - NROWS;
  if (ab < 512) {
    int id = ab * 256 + threadIdx.x;   // 0 .. 131071
    int which = id >> 16;
    int e = id & 65535;
    int rr = e >> 14, rem = e & 16383, ff = rem >> 7, o = rem & 127;
    const float* srcw = which ? W2 : W1;
    float* dst = which ? W2T : W1T;
    dst[e] = srcw[(rr * FDIM + o) * FDIM + ff];
    return;
  }
  int idx = (ab - 512) * 256 + threadIdx.x;   // 0 .. 511
  int rr = idx >> 7, ff = idx & 127;
  diagM[idx] = M[((size_t)(rr * FDIM + ff)) * FDIM + ff];
}

// ---------------------------------------------------------------------------
// K3: dense GEMM  C[n, oc] = sigmoid( sum_k A[n,k] * B[k, oc] ), K=512.
// Block: 8 rows x 128 cols; 256 threads = 128 cols x 2 K-halves.
// A-row loads are wave-uniform (L1 broadcast); B loads coalesced (L2-hot).
// ---------------------------------------------------------------------------
__device__ __forceinline__ void gemm_body(
    const float* __restrict__ A, const float* __restrict__ B,
    float* __restrict__ C, int n0, float (*red)[128]) {
  constexpr int KD = KDIM, KH = KDIM / 2, Ncol = FDIM;
  int o = threadIdx.x & 127;
  int half = threadIdx.x >> 7;
  const float* Ap = A + (size_t)n0 * KD + half * KH;
  const float* Bp = B + (size_t)half * KH * Ncol + o;
  float acc[8] = {0.f, 0.f, 0.f, 0.f, 0.f, 0.f, 0.f, 0.f};
#pragma unroll 2
  for (int k = 0; k < KH; k += 4) {
    float4 a0 = *(const float4*)(Ap + 0 * KD + k);
    float4 a1 = *(const float4*)(Ap + 1 * KD + k);
    float4 a2 = *(const float4*)(Ap + 2 * KD + k);
    float4 a3 = *(const float4*)(Ap + 3 * KD + k);
    float4 a4 = *(const float4*)(Ap + 4 * KD + k);
    float4 a5 = *(const float4*)(Ap + 5 * KD + k);
    float4 a6 = *(const float4*)(Ap + 6 * KD + k);
    float4 a7 = *(const float4*)(Ap + 7 * KD + k);
    float b0 = Bp[(size_t)(k + 0) * Ncol];
    float b1 = Bp[(size_t)(k + 1) * Ncol];
    float b2 = Bp[(size_t)(k + 2) * Ncol];
    float b3 = Bp[(size_t)(k + 3) * Ncol];
    acc[0] += a0.x * b0 + a0.y * b1 + a0.z * b2 + a0.w * b3;
    acc[1] += a1.x * b0 + a1.y * b1 + a1.z * b2 + a1.w * b3;
    acc[2] += a2.x * b0 + a2.y * b1 + a2.z * b2 + a2.w * b3;
    acc[3] += a3.x * b0 + a3.y * b1 + a3.z * b2 + a3.w * b3;
    acc[4] += a4.x * b0 + a4.y * b1 + a4.z * b2 + a4.w * b3;
    acc[5] += a5.x * b0 + a5.y * b1 + a5.z * b2 + a5.w * b3;
    acc[6] += a6.x * b0 + a6.y * b1 + a6.z * b2 + a6.w * b3;
    acc[7] += a7.x * b0 + a7.y * b1 + a7.z * b2 + a7.w * b3;
  }
  if (half) {
#pragma unroll
    for (int i = 0; i < 8; ++i) red[i][o] = acc[i];
  }
  __syncthreads();
  if (!half) {
#pragma unroll
    for (int i = 0; i < 8; ++i) {
      float v = acc[i] + red[i][o];
      v = 1.f / (1.f + __expf(-v));
      C[(size_t)(n0 + i) * Ncol + o] = v;
    }
  }
}

__global__ __launch_bounds__(256) void k_gemm(
    const float* __restrict__ A, const float* __restrict__ B,
    float* __restrict__ C) {
  __shared__ float red[8][128];
  gemm_body(A, B, C, blockIdx.x * 8, red);
}

// ---------------------------------------------------------------------------
// K_layer2: fused gather + GEMM for layer 2 (verified R1 structure).
// 4 nodes/block, 1024 blocks; agg tile in LDS (no global round-trip).
// ---------------------------------------------------------------------------
__global__ __launch_bounds__(256) void k_layer2(
    const unsigned short* __restrict__ cols, const int* __restrict__ cnt,
    const float* __restrict__ inv_deg, const float* __restrict__ h1,
    const float* __restrict__ W2T, float* __restrict__ h2) {
  int n0 = blockIdx.x * 4;
  __shared__ unsigned short lc[4][N_REL][MAXNZ];   // 4 KB
  __shared__ __align__(16) float aggL[4][KDIM];    // 8 KB
  __shared__ float red[4][128];                    // 2 KB
  {
    int i = threadIdx.x >> 4;       // row slot 0..15
    int t16 = threadIdx.x & 15;
    int nb = i >> 2, r = i & 3;
    int row = r * N_ENT + n0 + nb;
    int c = cnt[row];
    for (int j = t16; j < c; j += 16)
      lc[nb][r][j] = cols[(size_t)row * MAXNZ + j];
  }
  __syncthreads();
  {
    int l = threadIdx.x & 31;       // float4 lane
    int g = threadIdx.x >> 5;       // pair group 0..7
    const float* fp = h1 + l * 4;
#pragma unroll
    for (int q = 0; q < 2; ++q) {
      int pair = g + q * 8;         // 0..15 = nb*4 + r
      int nb = pair >> 2, r = pair & 3;
      int row = r * N_ENT + n0 + nb;
      int c = cnt[row];
      float w = inv_deg[row];
      float ax = 0.f, ay = 0.f, az = 0.f, aw = 0.f;
      int j = 0;
      for (; j + 2 <= c; j += 2) {
        float4 v0 = *(const float4*)(fp + (int)lc[nb][r][j] * FDIM);
        float4 v1 = *(const float4*)(fp + (int)lc[nb][r][j + 1] * FDIM);
        ax += v0.x + v1.x; ay += v0.y + v1.y;
        az += v0.z + v1.z; aw += v0.w + v1.w;
      }
      if (j < c) {
        float4 v = *(const float4*)(fp + (int)lc[nb][r][j] * FDIM);
        ax += v.x; ay += v.y; az += v.z; aw += v.w;
      }
      float4 res; res.x = ax * w; res.y = ay * w; res.z = az * w; res.w = aw * w;
      *(float4*)&aggL[nb][r * FDIM + l * 4] = res;
    }
  }
  __syncthreads();
  {
    constexpr int KH = KDIM / 2, Ncol = FDIM;
    int o = threadIdx.x & 127;
    int half = threadIdx.x >> 7;
    const float* Bp = W2T + (size_t)half * KH * Ncol + o;
    int kbase = half * KH;
    float acc[4] = {0.f, 0.f, 0.f, 0.f};
#pragma unroll 2
    for (int k = 0; k < KH; k += 4) {
      float4 a0 = *(const float4*)&aggL[0][kbase + k];
      float4 a1 = *(const float4*)&aggL[1][kbase + k];
      float4 a2 = *(const float4*)&aggL[2][kbase + k];
      float4 a3 = *(const float4*)&aggL[3][kbase + k];
      float b0 = Bp[(size_t)(k + 0) * Ncol];
      float b1 = Bp[(size_t)(k + 1) * Ncol];
      float b2 = Bp[(size_t)(k + 2) * Ncol];
      float b3 = Bp[(size_t)(k + 3) * Ncol];
      acc[0] += a0.x * b0 + a0.y * b1 + a0.z * b2 + a0.w * b3;
      acc[1] += a1.x * b0 + a1.y * b1 + a1.z * b2 + a1.w * b3;
      acc[2] += a2.x * b0 + a2.y * b1 + a2.z * b2 + a2.w * b3;
      acc[3] += a3.x * b0 + a3.y * b1 + a3.z * b2 + a3.w * b3;
    }
    if (half) {
#pragma unroll
      for (int i = 0; i < 4; ++i) red[i][o] = acc[i];
    }
    __syncthreads();
    if (!half) {
#pragma unroll
      for (int i = 0; i < 4; ++i) {
        float v = acc[i] + red[i][o];
        v = 1.f / (1.f + __expf(-v));
        h2[(size_t)(n0 + i) * Ncol + o] = v;
      }
    }
  }
}

// ---------------------------------------------------------------------------
// K4: diagonal DistMult: out[b] = sum_f h[e1,f] * diagM[rel,f] * h[e2,f].
// One wave per sample, 4 samples per block.
// ---------------------------------------------------------------------------
__global__ __launch_bounds__(256) void k_score(
    const float* __restrict__ h, const float* __restrict__ diagM,
    const int* __restrict__ e1, const int* __restrict__ rel,
    const int* __restrict__ e2, float* __restrict__ out) {
  int wave = threadIdx.x >> 6;
  int lane = threadIdx.x & 63;
  int b = blockIdx.x * 4 + wave;
  int a = e1[b], r = rel[b], c = e2[b];
  const float* hp = h + (size_t)a * FDIM;
  const float* dp = diagM + (size_t)r * FDIM;
  const float* gp = h + (size_t)c * FDIM;
  float v = hp[lane] * dp[lane] * gp[lane]
          + hp[lane + 64] * dp[lane + 64] * gp[lane + 64];
#pragma unroll
  for (int off = 32; off > 0; off >>= 1) v += __shfl_down(v, off, 64);
  if (lane == 0) out[b] = v;
}

// ---------------------------------------------------------------------------
extern "C" void kernel_launch(void* const* d_in, const int* in_sizes, int n_in,
                              void* d_out, int out_size, void* d_ws, size_t ws_size,
                              hipStream_t stream) {
  const float* feat = (const float*)d_in[0];
  const float* adj  = (const float*)d_in[1];
  const float* W1   = (const float*)d_in[2];
  const float* W2   = (const float*)d_in[3];
  const float* M    = (const float*)d_in[4];
  const int* e1     = (const int*)d_in[5];
  const int* rel    = (const int*)d_in[6];
  const int* e2     = (const int*)d_in[7];
  float* out = (float*)d_out;

  char* ws = (char*)d_ws;
  unsigned short* cols = (unsigned short*)(ws);                 // 4 MB
  int*   cnt  = (int*)  (ws + 4194304);                         // 64 KB
  float* inv  = (float*)(ws + 4259840);                         // 64 KB
  float* W1T  = (float*)(ws + 4325376);                         // 256 KB
  float* W2T  = (float*)(ws + 4587520);                         // 256 KB
  float* dM   = (float*)(ws + 4849664);                         // 2 KB
  float* agg  = (float*)(ws + 5111808);                         // 8 MB
  float* h1   = (float*)(ws + 13500416);                        // 2 MB
  float* h2   = (float*)(ws + 15597568);                        // 2 MB

  // prep: sparsify (atomic-free, coalesced) + fused layer-1 gather
  //       + weight transposes + relmat diag
  k_prep<<<NROWS + 514, 256, 0, stream>>>(
      W1, W2, M, adj, feat, W1T, W2T, dM, cols, cnt, inv, agg);

  // layer 1 matmul: h1 = sigmoid(agg @ W1T)
  k_gemm<<<N_ENT / 8, 256, 0, stream>>>(agg, W1T, h1);
  // layer 2 fused gather + matmul (agg tile in LDS): h2 = sigmoid(gather(h1) @ W2T)
  k_layer2<<<N_ENT / 4, 256, 0, stream>>>(cols, cnt, inv, h1, W2T, h2);
  // diagonal DistMult scores
  k_score<<<BATCH / 4, 256, 0, stream>>>(h2, dM, e1, rel, e2, out);
}